// Round 6
// baseline (230.093 us; speedup 1.0000x reference)
//
#include <hip/hip_runtime.h>

#define Hh 160
#define Ww 160
#define HW 25600
#define Bb 8
#define Cc 64
#define Oo 64
#define NPIX (Bb * HW)   // 204800

#define TROWS 8
#define TCOLS 36
#define TPIX (TROWS * TCOLS)   // 288 pixel-rows in the LDS tile

typedef __bf16 bf16x8 __attribute__((ext_vector_type(8)));
typedef float  f32x4  __attribute__((ext_vector_type(4)));
typedef float  f32x2  __attribute__((ext_vector_type(2)));

__device__ inline unsigned rnd_bf(float a) {
    unsigned u = __float_as_uint(a);
    return (u + 0x7FFFu + ((u >> 16) & 1u)) >> 16;   // RNE f32->bf16 (prep only)
}
__device__ inline unsigned pack_bf2(float a, float b) {
    unsigned ua = __float_as_uint(a) + 0x8000u;
    unsigned ub = __float_as_uint(b) + 0x8000u;
    return __builtin_amdgcn_perm(ub, ua, 0x07060302);
}
__device__ inline f32x2 up2(unsigned u) {
    f32x2 r;
    r.x = __uint_as_float(u << 16);
    r.y = __uint_as_float(u & 0xffff0000u);
    return r;
}
__device__ inline unsigned blend4(unsigned u00, unsigned u01, unsigned u10, unsigned u11,
                                  float w00, float w01, float w10, float w11) {
    f32x2 r = up2(u00) * w00 + up2(u01) * w01 + up2(u10) * w10 + up2(u11) * w11;
    return pack_bf2(r.x, r.y);
}
union UV { uint4 u; bf16x8 v; };
__device__ inline bf16x8 as_bf(uint4 u) { UV c; c.u = u; return c.v; }

// ---- prep: fragment-major weights so dcn's B-loads are contiguous 1KB/wave ----
// wtbf[k][f][lane][8]: f in 0..7, o = (f>>1)*16 + (lane&15),
//                      c = (lane>>4)*8 + (f&1)*32 + j
// wofbf[k][f][lane][8]: f in 0..3, same formula, o>=18 zero-padded.
__global__ __launch_bounds__(256) void prep_kernel(
    const float* __restrict__ w_dcn, const float* __restrict__ b_dcn,
    const float* __restrict__ w_off,
    const float* __restrict__ gamma, const float* __restrict__ beta,
    const float* __restrict__ run_mean, const float* __restrict__ run_var,
    unsigned short* __restrict__ wtbf, unsigned short* __restrict__ wofbf,
    float* __restrict__ scaleb)
{
    int i = blockIdx.x * 256 + threadIdx.x;
    if (i < 9 * 8 * 64 * 8) {              // 36864
        int j = i & 7, l = (i >> 3) & 63, f = (i >> 9) & 7, k = i >> 12;
        int o  = ((f >> 1) << 4) | (l & 15);
        int cc = ((l >> 4) << 3) + ((f & 1) << 5) + j;
        wtbf[i] = (unsigned short)rnd_bf(w_dcn[(o * Cc + cc) * 9 + k]);
    }
    if (i < 9 * 4 * 64 * 8) {              // 18432
        int j = i & 7, l = (i >> 3) & 63, f = (i >> 9) & 3, k = i >> 11;
        int o  = ((f >> 1) << 4) | (l & 15);
        int cc = ((l >> 4) << 3) + ((f & 1) << 5) + j;
        float v = (o < 18) ? w_off[(o * Cc + cc) * 9 + k] : 0.0f;
        wofbf[i] = (unsigned short)rnd_bf(v);
    }
    if (i < Oo) {
        float inv = gamma[i] * rsqrtf(run_var[i] + 1e-5f);
        scaleb[i]      = inv;
        scaleb[Oo + i] = b_dcn[i] * inv + (beta[i] - run_mean[i] * inv);
    }
}

// ---- transpose x: NCHW fp32 -> NHWC bf16; XCD swizzle matches dcn_kernel ------
__global__ __launch_bounds__(256, 4) void xpose_kernel(
    const float* __restrict__ x, unsigned short* __restrict__ xhwc)
{
    __shared__ float tile[64 * 65];
    int blk = blockIdx.x;                  // 3200
    int nb  = (blk & 7) * 400 + (blk >> 3);
    int b = nb / 400, hw0 = (nb % 400) * 64;
    int t = threadIdx.x;
    int lane = t & 63, grp = t >> 6;

    const float* xp = x + (size_t)b * Cc * HW + hw0 + lane;
#pragma unroll
    for (int i = 0; i < 16; ++i) {
        int c = i * 4 + grp;
        tile[lane * 65 + c] = xp[(size_t)c * HW];
    }
    __syncthreads();

    int px  = t >> 2;                      // 0..63
    int ch0 = (t & 3) * 16;
    const float* row = tile + px * 65 + ch0;
    unsigned u[8];
#pragma unroll
    for (int j = 0; j < 8; ++j) u[j] = pack_bf2(row[2 * j], row[2 * j + 1]);
    unsigned short* dst = xhwc + ((size_t)(b * HW + hw0 + px)) * 64 + ch0;
    *(uint4*)dst       = make_uint4(u[0], u[1], u[2], u[3]);
    *(uint4*)(dst + 8) = make_uint4(u[4], u[5], u[6], u[7]);
}

// swizzled tile read: pixel-row PIX, this lane's two 16B chunks (quad, quad+4)
#define TRD(PIX, LO, HI) do {                                                  \
    int _pp = (PIX);                                                           \
    int _s  = _pp & 7;                                                         \
    const char* _tb = (const char*)tile + _pp * 128;                           \
    LO = *(const uint4*)(_tb + ((quad ^ _s) << 4));                            \
    HI = *(const uint4*)(_tb + (((quad + 4) ^ _s) << 4));                      \
} while (0)

// ---- fused: offset-conv(MFMA) + deform-sample + projection(MFMA) + BN + ReLU --
// v6 (resubmit; previous run died to container infra, not kernel): 2D block =
// 4 rows x 32 cols of output (128 px, 512 thr, 8 waves) sharing ONE 8-row x
// 36-col LDS tile (36.9 KB -> 288 B/px vs v5's 720 B/px). LDS total 47.1 KB ->
// 3 blocks x 8 waves = 24 waves/CU (75% cap) vs v5's 12. Same single barrier,
// fragment-major global weights (L1-hot), rare wave-uniform global-gather
// fallback for out-of-window taps (bit-identical).
__global__ __launch_bounds__(512, 6) void dcn_kernel(
    const unsigned short* __restrict__ xhwc,
    const unsigned short* __restrict__ wtbf,    // [9][8][64][8]
    const unsigned short* __restrict__ wofbf,   // [9][4][64][8]
    const float* __restrict__ b_off,
    const float* __restrict__ scaleb,
    float* __restrict__ out)
{
    __shared__ __align__(16) unsigned short tile[TPIX * 64];  // 36864 B
    __shared__ __align__(16) float offb[128 * 20];            // 10240 B (47104)

    const int t = threadIdx.x;
    const int lane = t & 63, wv = t >> 6;      // wv 0..7
    const int m = lane & 15, quad = lane >> 4;

    int blk = blockIdx.x;                      // 1600
    int b   = blk & 7;                         // XCD swizzle: 1 image/XCD
    int nb  = blk >> 3;                        // 0..199
    int h0  = (nb / 5) * 4;                    // 4-row group
    int w0  = (nb % 5) * 32;                   // 32-px segment, row-aligned

    const int rloc  = wv >> 1;                 // wave's output row (0..3)
    const int chalf = (wv & 1) * 16;           // wave's col half
    const int h = h0 + rloc;
    const int w = w0 + chalf + m;              // this lane's pixel col
    const int pl_base = rloc * 32 + chalf;     // wave's first pixel id (0..127)

    const unsigned short* xb = xhwc + (size_t)b * HW * 64;
    const unsigned short* xq = xb + quad * 8;

    // ---- stage tile: rows h0-2..h0+5, cols w0-2..w0+33 (clamped), coalesced ---
    for (int id = t; id < TPIX * 8; id += 512) {
        int chunk = id & 7, pix = id >> 3;
        int r = pix / TCOLS, c = pix - r * TCOLS;
        int yr = min(max(h0 - 2 + r, 0), Hh - 1);
        int xc = min(max(w0 - 2 + c, 0), Ww - 1);
        uint4 v = *((const uint4*)(xb + ((size_t)yr * Ww + xc) * 64) + chunk);
        *(uint4*)((char*)tile + pix * 128 + ((chunk ^ (pix & 7)) << 4)) = v;
    }
    __syncthreads();   // the only barrier in this kernel

    // ================= phase 1: offset conv (A from tile, B global) ============
    f32x4 oa0 = {0,0,0,0}, oa1 = {0,0,0,0};
#pragma unroll
    for (int k = 0; k < 9; ++k) {
        int hp = h + k / 3 - 1, wp = w + (k % 3) - 1;
        bool ok = (hp >= 0) & (hp < Hh) & (wp >= 0) & (wp < Ww);
        int r = min(max(hp, 0), Hh - 1) - h0 + 2;      // in [0,7]
        int c = min(max(wp, 0), Ww - 1) - w0 + 2;      // in [0,35]
        uint4 r0, r1;
        TRD(r * TCOLS + c, r0, r1);
        if (!ok) { r0 = make_uint4(0,0,0,0); r1 = make_uint4(0,0,0,0); }
        bf16x8 a0 = as_bf(r0), a1 = as_bf(r1);

        const unsigned short* wf = wofbf + (size_t)(k * 4) * 512 + lane * 8;
        bf16x8 b00 = *(const bf16x8*)(wf);
        bf16x8 b01 = *(const bf16x8*)(wf + 512);
        bf16x8 b10 = *(const bf16x8*)(wf + 1024);
        bf16x8 b11 = *(const bf16x8*)(wf + 1536);
        oa0 = __builtin_amdgcn_mfma_f32_16x16x32_bf16(a0, b00, oa0, 0, 0, 0);
        oa0 = __builtin_amdgcn_mfma_f32_16x16x32_bf16(a1, b01, oa0, 0, 0, 0);
        oa1 = __builtin_amdgcn_mfma_f32_16x16x32_bf16(a0, b10, oa1, 0, 0, 0);
        oa1 = __builtin_amdgcn_mfma_f32_16x16x32_bf16(a1, b11, oa1, 0, 0, 0);
    }

    // offsets -> LDS transpose (wave-private rows) -> registers
    {
        float bo0 = b_off[m];
        float bo1 = (m < 2) ? b_off[16 + m] : 0.0f;
#pragma unroll
        for (int r = 0; r < 4; ++r) {
            int pp = pl_base + quad * 4 + r;
            offb[pp * 20 + m] = oa0[r] + bo0;
            if (m < 2) offb[pp * 20 + 16 + m] = oa1[r] + bo1;
        }
    }
    float oy[9], ox[9];
    {
        const int p20 = (pl_base + m) * 20;
#pragma unroll
        for (int k = 0; k < 9; ++k) {
            f32x2 o = *(const f32x2*)&offb[p20 + 2 * k];
            oy[k] = o.x; ox[k] = o.y;
        }
    }

    // ================= phase 2: deform sample (tile) + projection ==============
    f32x4 c0 = {0,0,0,0}, c1 = {0,0,0,0}, c2 = {0,0,0,0}, c3 = {0,0,0,0};
#pragma unroll
    for (int k = 0; k < 9; ++k) {
        float py = (float)(h + k / 3 - 1) + oy[k];
        float px = (float)(w + k % 3 - 1) + ox[k];
        float y0f = floorf(py), x0f = floorf(px);
        float fy = py - y0f, fx = px - x0f;
        int y0 = (int)y0f, x0i = (int)x0f;
        int y1 = y0 + 1, x1 = x0i + 1;
        bool vy0 = (y0 >= 0) & (y0 < Hh), vy1 = (y1 >= 0) & (y1 < Hh);
        bool vx0 = (x0i >= 0) & (x0i < Ww), vx1 = (x1 >= 0) & (x1 < Ww);
        float w00 = (vy0 & vx0) ? (1.0f - fy) * (1.0f - fx) : 0.0f;
        float w01 = (vy0 & vx1) ? (1.0f - fy) * fx : 0.0f;
        float w10 = (vy1 & vx0) ? fy * (1.0f - fx) : 0.0f;
        float w11 = (vy1 & vx1) ? fy * fx : 0.0f;
        int cy0 = min(max(y0, 0), Hh - 1), cy1 = min(max(y1, 0), Hh - 1);
        int cx0 = min(max(x0i, 0), Ww - 1), cx1 = min(max(x1, 0), Ww - 1);

        int r0 = cy0 - h0 + 2, r1 = cy1 - h0 + 2;      // tile coords
        int d0 = cx0 - w0 + 2, d1 = cx1 - w0 + 2;
        int inw = ((unsigned)r0 <= 7u) & ((unsigned)r1 <= 7u) &
                  ((unsigned)d0 <= 35u) & ((unsigned)d1 <= 35u);

        uint4 a00, h00, a01, h01, a10, h10, a11, h11;
        if (__all(inw)) {                              // fast path: LDS tile
            TRD(r0 * TCOLS + d0, a00, h00);
            TRD(r0 * TCOLS + d1, a01, h01);
            TRD(r1 * TCOLS + d0, a10, h10);
            TRD(r1 * TCOLS + d1, a11, h11);
        } else {                                       // rare: global gathers
            const unsigned short* s00 = xq + (size_t)(cy0 * Ww + cx0) * 64;
            const unsigned short* s01 = xq + (size_t)(cy0 * Ww + cx1) * 64;
            const unsigned short* s10 = xq + (size_t)(cy1 * Ww + cx0) * 64;
            const unsigned short* s11 = xq + (size_t)(cy1 * Ww + cx1) * 64;
            a00 = *(const uint4*)(s00); h00 = *(const uint4*)(s00 + 32);
            a01 = *(const uint4*)(s01); h01 = *(const uint4*)(s01 + 32);
            a10 = *(const uint4*)(s10); h10 = *(const uint4*)(s10 + 32);
            a11 = *(const uint4*)(s11); h11 = *(const uint4*)(s11 + 32);
        }

        uint4 o0, o1;
        o0.x = blend4(a00.x, a01.x, a10.x, a11.x, w00, w01, w10, w11);
        o0.y = blend4(a00.y, a01.y, a10.y, a11.y, w00, w01, w10, w11);
        o0.z = blend4(a00.z, a01.z, a10.z, a11.z, w00, w01, w10, w11);
        o0.w = blend4(a00.w, a01.w, a10.w, a11.w, w00, w01, w10, w11);
        o1.x = blend4(h00.x, h01.x, h10.x, h11.x, w00, w01, w10, w11);
        o1.y = blend4(h00.y, h01.y, h10.y, h11.y, w00, w01, w10, w11);
        o1.z = blend4(h00.z, h01.z, h10.z, h11.z, w00, w01, w10, w11);
        o1.w = blend4(h00.w, h01.w, h10.w, h11.w, w00, w01, w10, w11);
        bf16x8 A0 = as_bf(o0), A1 = as_bf(o1);

        const unsigned short* wf = wtbf + (size_t)(k * 8) * 512 + lane * 8;
        bf16x8 B0, B1;
        B0 = *(const bf16x8*)(wf);
        B1 = *(const bf16x8*)(wf + 512);
        c0 = __builtin_amdgcn_mfma_f32_16x16x32_bf16(A0, B0, c0, 0, 0, 0);
        c0 = __builtin_amdgcn_mfma_f32_16x16x32_bf16(A1, B1, c0, 0, 0, 0);
        B0 = *(const bf16x8*)(wf + 1024);
        B1 = *(const bf16x8*)(wf + 1536);
        c1 = __builtin_amdgcn_mfma_f32_16x16x32_bf16(A0, B0, c1, 0, 0, 0);
        c1 = __builtin_amdgcn_mfma_f32_16x16x32_bf16(A1, B1, c1, 0, 0, 0);
        B0 = *(const bf16x8*)(wf + 2048);
        B1 = *(const bf16x8*)(wf + 2560);
        c2 = __builtin_amdgcn_mfma_f32_16x16x32_bf16(A0, B0, c2, 0, 0, 0);
        c2 = __builtin_amdgcn_mfma_f32_16x16x32_bf16(A1, B1, c2, 0, 0, 0);
        B0 = *(const bf16x8*)(wf + 3072);
        B1 = *(const bf16x8*)(wf + 3584);
        c3 = __builtin_amdgcn_mfma_f32_16x16x32_bf16(A0, B0, c3, 0, 0, 0);
        c3 = __builtin_amdgcn_mfma_f32_16x16x32_bf16(A1, B1, c3, 0, 0, 0);
    }

    // ---- epilogue: BN + ReLU, direct float4 stores ----
#pragma unroll
    for (int nt = 0; nt < 4; ++nt) {
        f32x4 a = (nt == 0) ? c0 : (nt == 1) ? c1 : (nt == 2) ? c2 : c3;
        int o = nt * 16 + m;
        float sc = scaleb[o];
        float bs = scaleb[Oo + o];
        float4 r;
        r.x = fmaxf(a[0] * sc + bs, 0.0f);
        r.y = fmaxf(a[1] * sc + bs, 0.0f);
        r.z = fmaxf(a[2] * sc + bs, 0.0f);
        r.w = fmaxf(a[3] * sc + bs, 0.0f);
        float* op = out + ((size_t)b * Oo + o) * HW + h * Ww + w0 + chalf + quad * 4;
        *(float4*)op = r;
    }
}

extern "C" void kernel_launch(void* const* d_in, const int* in_sizes, int n_in,
                              void* d_out, int out_size, void* d_ws, size_t ws_size,
                              hipStream_t stream) {
    const float* x        = (const float*)d_in[0];
    const float* w_off    = (const float*)d_in[1];
    const float* b_off    = (const float*)d_in[2];
    const float* w_dcn    = (const float*)d_in[3];
    const float* b_dcn    = (const float*)d_in[4];
    const float* gamma    = (const float*)d_in[5];
    const float* beta     = (const float*)d_in[6];
    const float* run_mean = (const float*)d_in[7];
    const float* run_var  = (const float*)d_in[8];
    float* out = (float*)d_out;

    // workspace: xhwc (26.2 MB) | wtbf | wofbf | scaleb
    unsigned short* xhwc  = (unsigned short*)d_ws;
    unsigned short* wtbf  = xhwc + (size_t)NPIX * 64;     // 9*8*64*8 bf16
    unsigned short* wofbf = wtbf + 9 * 8 * 64 * 8;        // 9*4*64*8 bf16
    float* scaleb         = (float*)(wofbf + 9 * 4 * 64 * 8);  // 128 floats

    prep_kernel<<<(9 * 8 * 64 * 8 + 255) / 256, 256, 0, stream>>>(
        w_dcn, b_dcn, w_off, gamma, beta, run_mean, run_var, wtbf, wofbf, scaleb);

    xpose_kernel<<<NPIX / 64, 256, 0, stream>>>(x, xhwc);

    dcn_kernel<<<NPIX / 128, 512, 0, stream>>>(xhwc, wtbf, wofbf, b_off, scaleb, out);
}

// Round 7
// 209.712 us; speedup vs baseline: 1.0972x; 1.0972x over previous
//
#include <hip/hip_runtime.h>

#define Hh 160
#define Ww 160
#define HW 25600
#define Bb 8
#define Cc 64
#define Oo 64
#define NPIX (Bb * HW)   // 204800

#define TROWS 8
#define TCOLS 36
#define TPIX (TROWS * TCOLS)   // 288 pixel-rows in the LDS tile

typedef __bf16 bf16x8 __attribute__((ext_vector_type(8)));
typedef float  f32x4  __attribute__((ext_vector_type(4)));
typedef float  f32x2  __attribute__((ext_vector_type(2)));

__device__ inline unsigned rnd_bf(float a) {
    unsigned u = __float_as_uint(a);
    return (u + 0x7FFFu + ((u >> 16) & 1u)) >> 16;   // RNE f32->bf16 (prep only)
}
__device__ inline unsigned pack_bf2(float a, float b) {
    unsigned ua = __float_as_uint(a) + 0x8000u;
    unsigned ub = __float_as_uint(b) + 0x8000u;
    return __builtin_amdgcn_perm(ub, ua, 0x07060302);
}
__device__ inline f32x2 up2(unsigned u) {
    f32x2 r;
    r.x = __uint_as_float(u << 16);
    r.y = __uint_as_float(u & 0xffff0000u);
    return r;
}
__device__ inline unsigned blend4(unsigned u00, unsigned u01, unsigned u10, unsigned u11,
                                  float w00, float w01, float w10, float w11) {
    f32x2 r = up2(u00) * w00 + up2(u01) * w01 + up2(u10) * w10 + up2(u11) * w11;
    return pack_bf2(r.x, r.y);
}
union UV { uint4 u; bf16x8 v; };
__device__ inline bf16x8 as_bf(uint4 u) { UV c; c.u = u; return c.v; }

// ---- prep: fragment-major weights so dcn's B-loads are contiguous 1KB/wave ----
// wtbf[k][f][lane][8]: f in 0..7, o = (f>>1)*16 + (lane&15),
//                      c = (lane>>4)*8 + (f&1)*32 + j
// wofbf[k][f][lane][8]: f in 0..3, same formula, o>=18 zero-padded.
__global__ __launch_bounds__(256) void prep_kernel(
    const float* __restrict__ w_dcn, const float* __restrict__ b_dcn,
    const float* __restrict__ w_off,
    const float* __restrict__ gamma, const float* __restrict__ beta,
    const float* __restrict__ run_mean, const float* __restrict__ run_var,
    unsigned short* __restrict__ wtbf, unsigned short* __restrict__ wofbf,
    float* __restrict__ scaleb)
{
    int i = blockIdx.x * 256 + threadIdx.x;
    if (i < 9 * 8 * 64 * 8) {              // 36864
        int j = i & 7, l = (i >> 3) & 63, f = (i >> 9) & 7, k = i >> 12;
        int o  = ((f >> 1) << 4) | (l & 15);
        int cc = ((l >> 4) << 3) + ((f & 1) << 5) + j;
        wtbf[i] = (unsigned short)rnd_bf(w_dcn[(o * Cc + cc) * 9 + k]);
    }
    if (i < 9 * 4 * 64 * 8) {              // 18432
        int j = i & 7, l = (i >> 3) & 63, f = (i >> 9) & 3, k = i >> 11;
        int o  = ((f >> 1) << 4) | (l & 15);
        int cc = ((l >> 4) << 3) + ((f & 1) << 5) + j;
        float v = (o < 18) ? w_off[(o * Cc + cc) * 9 + k] : 0.0f;
        wofbf[i] = (unsigned short)rnd_bf(v);
    }
    if (i < Oo) {
        float inv = gamma[i] * rsqrtf(run_var[i] + 1e-5f);
        scaleb[i]      = inv;
        scaleb[Oo + i] = b_dcn[i] * inv + (beta[i] - run_mean[i] * inv);
    }
}

// swizzled tile read: pixel-row PIX, this lane's two 16B chunks (quad, quad+4)
#define TRD(PIX, LO, HI) do {                                                  \
    int _pp = (PIX);                                                           \
    int _s  = _pp & 7;                                                         \
    const char* _tb = (const char*)tile + _pp * 128;                           \
    LO = *(const uint4*)(_tb + ((quad ^ _s) << 4));                            \
    HI = *(const uint4*)(_tb + (((quad + 4) ^ _s) << 4));                      \
} while (0)

// rare out-of-window gather straight from NCHW x, with the SAME round-half-up
// bf16 conversion as the staged tile (bit-identical to the old xhwc path).
#define GATHF(CY, CX, A, H) do {                                               \
    const float* _sp = xbf + (size_t)(quad * 8) * HW + ((CY) * Ww + (CX));     \
    A = make_uint4(pack_bf2(_sp[0],      _sp[HW]),                             \
                   pack_bf2(_sp[2 * HW], _sp[3 * HW]),                         \
                   pack_bf2(_sp[4 * HW], _sp[5 * HW]),                         \
                   pack_bf2(_sp[6 * HW], _sp[7 * HW]));                        \
    const float* _hp = _sp + (size_t)32 * HW;                                  \
    H = make_uint4(pack_bf2(_hp[0],      _hp[HW]),                             \
                   pack_bf2(_hp[2 * HW], _hp[3 * HW]),                         \
                   pack_bf2(_hp[4 * HW], _hp[5 * HW]),                         \
                   pack_bf2(_hp[6 * HW], _hp[7 * HW]));                        \
} while (0)

// ---- fused: offset-conv(MFMA) + deform-sample + projection(MFMA) + BN + ReLU --
// v7: xpose_kernel is GONE. Staging reads x (NCHW fp32) directly and does the
// channel-transpose + bf16 pack while writing the swizzled LDS tile (scalar
// pair loads, coalesced along w). Saves xpose's 79 MB HBM round-trip + a
// dispatch. Epilogue now routes accumulators through LDS (obuf[o][132-pad])
// so `out` is written in FULLY-COVERED 128B lines per wave — v6's counters
// showed 2.45x write amplification + 40 MB RMW fetch from 64B partial-line
// stores at high occupancy.
__global__ __launch_bounds__(512, 6) void dcn_kernel(
    const float* __restrict__ x,
    const unsigned short* __restrict__ wtbf,    // [9][8][64][8]
    const unsigned short* __restrict__ wofbf,   // [9][4][64][8]
    const float* __restrict__ b_off,
    const float* __restrict__ scaleb,
    float* __restrict__ out)
{
    __shared__ __align__(16) unsigned short tile[TPIX * 64];  // 36864 B
    __shared__ __align__(16) float offb[128 * 20];            // 10240 B (47104)

    const int t = threadIdx.x;
    const int lane = t & 63, wv = t >> 6;      // wv 0..7
    const int m = lane & 15, quad = lane >> 4;

    int blk = blockIdx.x;                      // 1600
    int b   = blk & 7;                         // XCD swizzle: 1 image/XCD
    int nb  = blk >> 3;                        // 0..199
    int h0  = (nb / 5) * 4;                    // 4-row group
    int w0  = (nb % 5) * 32;                   // 32-px segment, row-aligned

    const int rloc  = wv >> 1;                 // wave's output row (0..3)
    const int chalf = (wv & 1) * 16;           // wave's col half
    const int h = h0 + rloc;
    const int w = w0 + chalf + m;              // this lane's pixel col
    const int pl_base = rloc * 32 + chalf;     // wave's first pixel id (0..127)

    const float* xbf = x + (size_t)b * Cc * HW;

    // ---- stage tile from NCHW x: transpose + bf16 pack, coalesced along w ----
    // work id = ((c2*8 + r)*36 + col): consecutive lanes -> consecutive cols.
    // 9216 b32 writes = 512 thr x 18 iters exactly (uniform, no divergence).
#pragma unroll
    for (int it = 0; it < 18; ++it) {
        int id  = t + it * 512;
        int col = id % 36;
        int rr  = id / 36;                 // c2*8 + r
        int r   = rr & 7;
        int c2  = rr >> 3;                 // channel pair 0..31
        int yr = min(max(h0 - 2 + r, 0), Hh - 1);
        int xc = min(max(w0 - 2 + col, 0), Ww - 1);
        const float* sp = xbf + (size_t)(c2 * 2) * HW + (yr * Ww + xc);
        unsigned v = pack_bf2(sp[0], sp[HW]);
        int pix = r * TCOLS + col;
        *(unsigned*)((char*)tile + pix * 128
                     + ((((c2 >> 2) ^ (pix & 7)) << 4) + ((c2 & 3) << 2))) = v;
    }
    __syncthreads();

    // ================= phase 1: offset conv (A from tile, B global) ============
    f32x4 oa0 = {0,0,0,0}, oa1 = {0,0,0,0};
#pragma unroll
    for (int k = 0; k < 9; ++k) {
        int hp = h + k / 3 - 1, wp = w + (k % 3) - 1;
        bool ok = (hp >= 0) & (hp < Hh) & (wp >= 0) & (wp < Ww);
        int r = min(max(hp, 0), Hh - 1) - h0 + 2;      // in [0,7]
        int c = min(max(wp, 0), Ww - 1) - w0 + 2;      // in [0,35]
        uint4 r0, r1;
        TRD(r * TCOLS + c, r0, r1);
        if (!ok) { r0 = make_uint4(0,0,0,0); r1 = make_uint4(0,0,0,0); }
        bf16x8 a0 = as_bf(r0), a1 = as_bf(r1);

        const unsigned short* wf = wofbf + (size_t)(k * 4) * 512 + lane * 8;
        bf16x8 b00 = *(const bf16x8*)(wf);
        bf16x8 b01 = *(const bf16x8*)(wf + 512);
        bf16x8 b10 = *(const bf16x8*)(wf + 1024);
        bf16x8 b11 = *(const bf16x8*)(wf + 1536);
        oa0 = __builtin_amdgcn_mfma_f32_16x16x32_bf16(a0, b00, oa0, 0, 0, 0);
        oa0 = __builtin_amdgcn_mfma_f32_16x16x32_bf16(a1, b01, oa0, 0, 0, 0);
        oa1 = __builtin_amdgcn_mfma_f32_16x16x32_bf16(a0, b10, oa1, 0, 0, 0);
        oa1 = __builtin_amdgcn_mfma_f32_16x16x32_bf16(a1, b11, oa1, 0, 0, 0);
    }

    // offsets -> LDS transpose (wave-private rows) -> registers
    {
        float bo0 = b_off[m];
        float bo1 = (m < 2) ? b_off[16 + m] : 0.0f;
#pragma unroll
        for (int r = 0; r < 4; ++r) {
            int pp = pl_base + quad * 4 + r;
            offb[pp * 20 + m] = oa0[r] + bo0;
            if (m < 2) offb[pp * 20 + 16 + m] = oa1[r] + bo1;
        }
    }
    float oy[9], ox[9];
    {
        const int p20 = (pl_base + m) * 20;
#pragma unroll
        for (int k = 0; k < 9; ++k) {
            f32x2 o = *(const f32x2*)&offb[p20 + 2 * k];
            oy[k] = o.x; ox[k] = o.y;
        }
    }

    // ================= phase 2: deform sample (tile) + projection ==============
    f32x4 c0 = {0,0,0,0}, c1 = {0,0,0,0}, c2 = {0,0,0,0}, c3 = {0,0,0,0};
#pragma unroll
    for (int k = 0; k < 9; ++k) {
        float py = (float)(h + k / 3 - 1) + oy[k];
        float px = (float)(w + k % 3 - 1) + ox[k];
        float y0f = floorf(py), x0f = floorf(px);
        float fy = py - y0f, fx = px - x0f;
        int y0 = (int)y0f, x0i = (int)x0f;
        int y1 = y0 + 1, x1 = x0i + 1;
        bool vy0 = (y0 >= 0) & (y0 < Hh), vy1 = (y1 >= 0) & (y1 < Hh);
        bool vx0 = (x0i >= 0) & (x0i < Ww), vx1 = (x1 >= 0) & (x1 < Ww);
        float w00 = (vy0 & vx0) ? (1.0f - fy) * (1.0f - fx) : 0.0f;
        float w01 = (vy0 & vx1) ? (1.0f - fy) * fx : 0.0f;
        float w10 = (vy1 & vx0) ? fy * (1.0f - fx) : 0.0f;
        float w11 = (vy1 & vx1) ? fy * fx : 0.0f;
        int cy0 = min(max(y0, 0), Hh - 1), cy1 = min(max(y1, 0), Hh - 1);
        int cx0 = min(max(x0i, 0), Ww - 1), cx1 = min(max(x1, 0), Ww - 1);

        int r0 = cy0 - h0 + 2, r1 = cy1 - h0 + 2;      // tile coords
        int d0 = cx0 - w0 + 2, d1 = cx1 - w0 + 2;
        int inw = ((unsigned)r0 <= 7u) & ((unsigned)r1 <= 7u) &
                  ((unsigned)d0 <= 35u) & ((unsigned)d1 <= 35u);

        uint4 a00, h00, a01, h01, a10, h10, a11, h11;
        if (__all(inw)) {                              // fast path: LDS tile
            TRD(r0 * TCOLS + d0, a00, h00);
            TRD(r0 * TCOLS + d1, a01, h01);
            TRD(r1 * TCOLS + d0, a10, h10);
            TRD(r1 * TCOLS + d1, a11, h11);
        } else {                                       // rare: global gathers
            GATHF(cy0, cx0, a00, h00);
            GATHF(cy0, cx1, a01, h01);
            GATHF(cy1, cx0, a10, h10);
            GATHF(cy1, cx1, a11, h11);
        }

        uint4 o0, o1;
        o0.x = blend4(a00.x, a01.x, a10.x, a11.x, w00, w01, w10, w11);
        o0.y = blend4(a00.y, a01.y, a10.y, a11.y, w00, w01, w10, w11);
        o0.z = blend4(a00.z, a01.z, a10.z, a11.z, w00, w01, w10, w11);
        o0.w = blend4(a00.w, a01.w, a10.w, a11.w, w00, w01, w10, w11);
        o1.x = blend4(h00.x, h01.x, h10.x, h11.x, w00, w01, w10, w11);
        o1.y = blend4(h00.y, h01.y, h10.y, h11.y, w00, w01, w10, w11);
        o1.z = blend4(h00.z, h01.z, h10.z, h11.z, w00, w01, w10, w11);
        o1.w = blend4(h00.w, h01.w, h10.w, h11.w, w00, w01, w10, w11);
        bf16x8 A0 = as_bf(o0), A1 = as_bf(o1);

        const unsigned short* wf = wtbf + (size_t)(k * 8) * 512 + lane * 8;
        bf16x8 B0, B1;
        B0 = *(const bf16x8*)(wf);
        B1 = *(const bf16x8*)(wf + 512);
        c0 = __builtin_amdgcn_mfma_f32_16x16x32_bf16(A0, B0, c0, 0, 0, 0);
        c0 = __builtin_amdgcn_mfma_f32_16x16x32_bf16(A1, B1, c0, 0, 0, 0);
        B0 = *(const bf16x8*)(wf + 1024);
        B1 = *(const bf16x8*)(wf + 1536);
        c1 = __builtin_amdgcn_mfma_f32_16x16x32_bf16(A0, B0, c1, 0, 0, 0);
        c1 = __builtin_amdgcn_mfma_f32_16x16x32_bf16(A1, B1, c1, 0, 0, 0);
        B0 = *(const bf16x8*)(wf + 2048);
        B1 = *(const bf16x8*)(wf + 2560);
        c2 = __builtin_amdgcn_mfma_f32_16x16x32_bf16(A0, B0, c2, 0, 0, 0);
        c2 = __builtin_amdgcn_mfma_f32_16x16x32_bf16(A1, B1, c2, 0, 0, 0);
        B0 = *(const bf16x8*)(wf + 3072);
        B1 = *(const bf16x8*)(wf + 3584);
        c3 = __builtin_amdgcn_mfma_f32_16x16x32_bf16(A0, B0, c3, 0, 0, 0);
        c3 = __builtin_amdgcn_mfma_f32_16x16x32_bf16(A1, B1, c3, 0, 0, 0);
    }

    // ---- epilogue: BN+ReLU in regs, LDS re-layout, full-128B-line stores ----
    __syncthreads();                       // all tile reads done; reuse as obuf
    float* obuf = (float*)tile;            // [o][132] floats = 33792 B <= 36864
#pragma unroll
    for (int nt = 0; nt < 4; ++nt) {
        f32x4 a = (nt == 0) ? c0 : (nt == 1) ? c1 : (nt == 2) ? c2 : c3;
        int o = nt * 16 + m;
        float sc = scaleb[o];
        float bs = scaleb[Oo + o];
        f32x4 r;
        r[0] = fmaxf(a[0] * sc + bs, 0.0f);
        r[1] = fmaxf(a[1] * sc + bs, 0.0f);
        r[2] = fmaxf(a[2] * sc + bs, 0.0f);
        r[3] = fmaxf(a[3] * sc + bs, 0.0f);
        *(f32x4*)&obuf[o * 132 + pl_base + quad * 4] = r;
    }
    __syncthreads();
    {
        int o = t >> 3, part = t & 7;      // 64 o x 8 x 16-float segments
        const float* src = obuf + o * 132 + part * 16;
        float* dst = out + ((size_t)b * Oo + o) * HW
                   + (h0 + (part >> 1)) * Ww + w0 + (part & 1) * 16;
        float4 v0 = *(const float4*)(src);
        float4 v1 = *(const float4*)(src + 4);
        float4 v2 = *(const float4*)(src + 8);
        float4 v3 = *(const float4*)(src + 12);
        *(float4*)(dst)      = v0;
        *(float4*)(dst + 4)  = v1;
        *(float4*)(dst + 8)  = v2;
        *(float4*)(dst + 12) = v3;
    }
}

extern "C" void kernel_launch(void* const* d_in, const int* in_sizes, int n_in,
                              void* d_out, int out_size, void* d_ws, size_t ws_size,
                              hipStream_t stream) {
    const float* x        = (const float*)d_in[0];
    const float* w_off    = (const float*)d_in[1];
    const float* b_off    = (const float*)d_in[2];
    const float* w_dcn    = (const float*)d_in[3];
    const float* b_dcn    = (const float*)d_in[4];
    const float* gamma    = (const float*)d_in[5];
    const float* beta     = (const float*)d_in[6];
    const float* run_mean = (const float*)d_in[7];
    const float* run_var  = (const float*)d_in[8];
    float* out = (float*)d_out;

    // workspace: wtbf | wofbf | scaleb (xhwc eliminated with xpose)
    unsigned short* wtbf  = (unsigned short*)d_ws;        // 9*8*64*8 bf16
    unsigned short* wofbf = wtbf + 9 * 8 * 64 * 8;        // 9*4*64*8 bf16
    float* scaleb         = (float*)(wofbf + 9 * 4 * 64 * 8);  // 128 floats

    prep_kernel<<<(9 * 8 * 64 * 8 + 255) / 256, 256, 0, stream>>>(
        w_dcn, b_dcn, w_off, gamma, beta, run_mean, run_var, wtbf, wofbf, scaleb);

    dcn_kernel<<<NPIX / 128, 512, 0, stream>>>(x, wtbf, wofbf, b_off, scaleb, out);
}